// Round 2
// baseline (122.212 us; speedup 1.0000x reference)
//
#include <hip/hip_runtime.h>
#include <hip/hip_bf16.h>

// Problem constants
#define B    2
#define CIN  256
#define H    56
#define W    56
#define OUTC 256
#define KS   7
#define PAD  3
#define G    8
#define CG   32
#define HP   62           // H + 2*PAD
#define WP   62
#define P1   (H * W)      // 3136
#define P2   (HP * WP)    // 3844

typedef __attribute__((ext_vector_type(2))) _Float16 h2;
typedef __attribute__((ext_vector_type(8))) _Float16 f16x8;
typedef __attribute__((ext_vector_type(8))) unsigned short ushort8;
typedef __attribute__((ext_vector_type(4))) float f32x4;

__device__ inline unsigned short f2h(float f) {    // RNE float->fp16 bits
    const _Float16 h = (_Float16)f;
    return *(const unsigned short*)&h;
}

__device__ inline float fdot2(h2 a, h2 b, float c) {
#if defined(__has_builtin)
#if __has_builtin(__builtin_amdgcn_fdot2)
    return __builtin_amdgcn_fdot2(a, b, c, false);
#else
    return c + (float)a[0] * (float)b[0] + (float)a[1] * (float)b[1];
#endif
#else
    return c + (float)a[0] * (float)b[0] + (float)a[1] * (float)b[1];
#endif
}

__device__ inline float dot8(const f16x8 q, const f16x8 k, float s) {
    s = fdot2((h2){q[0], q[1]}, (h2){k[0], k[1]}, s);
    s = fdot2((h2){q[2], q[3]}, (h2){k[2], k[3]}, s);
    s = fdot2((h2){q[4], q[5]}, (h2){k[4], k[5]}, s);
    s = fdot2((h2){q[6], q[7]}, (h2){k[6], k[7]}, s);
    return s;
}

// ---------------------------------------------------------------------------
// Fused fp32->fp16 + MFMA GEMM (one launch): grid (31, 6, B).  (unchanged)
//   y<2  : q GEMM  (w_q x fm_t1), x<25 only (N=P1)
//   y>=2 : kv GEMM (w_k rows 0..255, w_v rows 256..511 x padded fm_t0, N=P2)
// 128x128 tile, 4 waves, BK=32; staging converts fp32 inputs inline.
// Epilogue writes fp16 INTERLEAVED planes: base[((b*8+g)*4+sub)*Pstr + n]*8+l8.
// ---------------------------------------------------------------------------
#define ASTR 40
__global__ __launch_bounds__(256, 2) void gemm_kernel(const float* __restrict__ fm,
                                                      const float* __restrict__ wq,
                                                      const float* __restrict__ wk,
                                                      const float* __restrict__ wv,
                                                      unsigned short* __restrict__ qi,
                                                      unsigned short* __restrict__ ki,
                                                      unsigned short* __restrict__ vi) {
    const int b = blockIdx.z;
    const bool isQ = blockIdx.y < 2;
    if (isQ && blockIdx.x >= 25) return;
    const int o0 = (isQ ? blockIdx.y : (blockIdx.y - 2)) * 128;   // 0..383
    const int n0 = blockIdx.x * 128;
    const int Nreal = isQ ? P1 : P2;
    const int Pstr  = isQ ? P1 : P2;

    const float* Wsrc;
    int orow0;
    if (isQ)            { Wsrc = wq; orow0 = o0; }
    else if (o0 < 256)  { Wsrc = wk; orow0 = o0; }
    else                { Wsrc = wv; orow0 = o0 - 256; }

    __shared__ unsigned short Alds[128 * ASTR];
    __shared__ unsigned short Blds[128 * ASTR];
    const int tid = threadIdx.x;
    const int lane = tid & 63;
    const int wave = tid >> 6;
    const int wr = (wave >> 1) * 64;
    const int wc = (wave & 1) * 64;
    const int lrow = lane & 15;
    const int quad = lane >> 4;

    const int arow = tid & 127;
    const int akc  = (tid >> 7) * 16;

    const int n = n0 + arow;
    int srcoff = -1;
    if (isQ) {
        if (n < P1) srcoff = n;
    } else {
        if (n < P2) {
            const int y = n / WP, x = n - y * WP;
            const int iy = y - PAD, ix = x - PAD;
            if (iy >= 0 && iy < H && ix >= 0 && ix < W) srcoff = iy * W + ix;
        }
    }
    const float* fmB = fm + ((size_t)b * (2 * CIN) + (isQ ? CIN : 0)) * P1;
    const float* wrow = Wsrc + (size_t)orow0 * CIN + (size_t)arow * CIN + akc;

    unsigned short* alp = Alds + arow * ASTR + akc;
    unsigned short* blp = Blds + arow * ASTR + akc;

    f32x4 acc[4][4] = {};

    float av[16], bv[16];
    {
        const float4 a0 = ((const float4*)wrow)[0];
        const float4 a1 = ((const float4*)wrow)[1];
        const float4 a2 = ((const float4*)wrow)[2];
        const float4 a3 = ((const float4*)wrow)[3];
        av[0]=a0.x; av[1]=a0.y; av[2]=a0.z; av[3]=a0.w;
        av[4]=a1.x; av[5]=a1.y; av[6]=a1.z; av[7]=a1.w;
        av[8]=a2.x; av[9]=a2.y; av[10]=a2.z; av[11]=a2.w;
        av[12]=a3.x; av[13]=a3.y; av[14]=a3.z; av[15]=a3.w;
        #pragma unroll
        for (int j = 0; j < 16; ++j)
            bv[j] = (srcoff >= 0) ? fmB[(size_t)(akc + j) * P1 + srcoff] : 0.f;
    }

    for (int kb = 0; kb < CIN / 32; ++kb) {
        {
            f16x8 p0, p1, p2, p3;
            #pragma unroll
            for (int j = 0; j < 8; ++j) {
                p0[j] = (_Float16)av[j];
                p1[j] = (_Float16)av[8 + j];
                p2[j] = (_Float16)bv[j];
                p3[j] = (_Float16)bv[8 + j];
            }
            *(f16x8*)(alp)     = p0;
            *(f16x8*)(alp + 8) = p1;
            *(f16x8*)(blp)     = p2;
            *(f16x8*)(blp + 8) = p3;
        }
        __syncthreads();
        if (kb < CIN / 32 - 1) {
            const int c0 = (kb + 1) * 32 + akc;
            const float* wnext = wrow + (kb + 1) * 32;
            const float4 a0 = ((const float4*)wnext)[0];
            const float4 a1 = ((const float4*)wnext)[1];
            const float4 a2 = ((const float4*)wnext)[2];
            const float4 a3 = ((const float4*)wnext)[3];
            av[0]=a0.x; av[1]=a0.y; av[2]=a0.z; av[3]=a0.w;
            av[4]=a1.x; av[5]=a1.y; av[6]=a1.z; av[7]=a1.w;
            av[8]=a2.x; av[9]=a2.y; av[10]=a2.z; av[11]=a2.w;
            av[12]=a3.x; av[13]=a3.y; av[14]=a3.z; av[15]=a3.w;
            #pragma unroll
            for (int j = 0; j < 16; ++j)
                bv[j] = (srcoff >= 0) ? fmB[(size_t)(c0 + j) * P1 + srcoff] : 0.f;
        }
        f16x8 af[4], bfr[4];
        #pragma unroll
        for (int mi = 0; mi < 4; ++mi)
            af[mi] = *(const f16x8*)&Alds[(wr + mi * 16 + lrow) * ASTR + quad * 8];
        #pragma unroll
        for (int ni = 0; ni < 4; ++ni)
            bfr[ni] = *(const f16x8*)&Blds[(wc + ni * 16 + lrow) * ASTR + quad * 8];
        #pragma unroll
        for (int mi = 0; mi < 4; ++mi)
            #pragma unroll
            for (int ni = 0; ni < 4; ++ni)
                acc[mi][ni] = __builtin_amdgcn_mfma_f32_16x16x32_f16(af[mi], bfr[ni], acc[mi][ni], 0, 0, 0);
        __syncthreads();
    }

    #pragma unroll
    for (int mi = 0; mi < 4; ++mi) {
        const int gmBase = o0 + wr + mi * 16 + quad * 4;
        int ch0;
        unsigned short* base;
        if (isQ)               { ch0 = gmBase;       base = qi; }
        else if (gmBase < 256) { ch0 = gmBase;       base = ki; }
        else                   { ch0 = gmBase - 256; base = vi; }
        const int g   = ch0 >> 5;
        const int sub = (ch0 >> 3) & 3;
        const int l8  = ch0 & 7;
        unsigned short* pbase = base + ((((size_t)b * 8 + g) * 4 + sub) * Pstr) * 8 + l8;
        #pragma unroll
        for (int ni = 0; ni < 4; ++ni) {
            const int gn = n0 + wc + ni * 16 + lrow;
            if (gn < Nreal) {
                ushort4 pk;
                pk.x = f2h(acc[mi][ni][0]);
                pk.y = f2h(acc[mi][ni][1]);
                pk.z = f2h(acc[mi][ni][2]);
                pk.w = f2h(acc[mi][ni][3]);
                *(ushort4*)(pbase + (size_t)gn * 8) = pk;
            }
        }
    }
}

// ---------------------------------------------------------------------------
// Grouped 7x7 attention v4: thread = (pixel, sub). 4x the waves of v3.
// Each thread handles 8 channels (one f16x8 sub-plane): partial bias +
// partial QK logits over its 8 ch, then a 2-step __shfl_xor butterfly
// (masks 1,2) sums the 4 sub-partials -> all 4 lanes of a pixel-quad hold
// identical full logits. Softmax duplicated (cheap); PV splits by sub.
// Threads per (b,g): P1*4 = 12544 = 49 blocks x 256 exactly (no tail).
// Grid (49, G, B) = 784 blocks = 3136 waves (~3.1/SIMD) -> latency hidden.
// No LDS, no barriers; K/V reads are L1/L2-resident (written by gemm).
// ---------------------------------------------------------------------------
__global__ __launch_bounds__(256) void attn_kernel(const unsigned short* __restrict__ qi,
                                                   const unsigned short* __restrict__ ki,
                                                   const unsigned short* __restrict__ vi,
                                                   const float* __restrict__ rel_h,
                                                   const float* __restrict__ rel_w,
                                                   float* __restrict__ out) {
    const int b = blockIdx.z;
    const int g = blockIdx.y;
    const int t = blockIdx.x * 256 + threadIdx.x;   // 0..12543
    const int s = t & 3;                            // sub-plane 0..3
    const int p = t >> 2;                           // pixel 0..3135

    const int h = p / W;
    const int w = p - h * W;
    const int pos0 = h * WP + w;                    // window origin in padded grid
    const size_t plane = ((size_t)b * G + g) * 4 + s;

    // ---- load this sub's 8 q channels ----
    const f16x8 q = *(const f16x8*)(qi + (plane * P1 + p) * 8);

    // ---- partial bias over this sub's 8 channels (rel uniform -> SGPR) ----
    const float* rel = (g < 4) ? (rel_h + (size_t)g * CG * KS)
                               : (rel_w + (size_t)(g - 4) * CG * KS);
    float bd[KS];
    #pragma unroll
    for (int t7 = 0; t7 < KS; ++t7) {
        float s0 = 0.f;
        #pragma unroll
        for (int j = 0; j < 8; ++j)
            s0 += (float)q[j] * rel[(s * 8 + j) * KS + t7];
        bd[t7] = s0;
    }

    float logits[KS * KS];
    #pragma unroll
    for (int i = 0; i < KS; ++i)
        #pragma unroll
        for (int j = 0; j < KS; ++j)
            logits[i * KS + j] = (g < 4) ? bd[i] : bd[j];

    // ---- partial QK^T over this sub: 49 taps ----
    {
        const unsigned short* kp = ki + (plane * P2 + pos0) * 8;
        #pragma unroll
        for (int i = 0; i < KS; ++i) {
            const unsigned short* kr = kp + i * WP * 8;
            #pragma unroll
            for (int j = 0; j < KS; ++j) {
                const f16x8 kv = *(const f16x8*)(kr + j * 8);
                logits[i * KS + j] = dot8(q, kv, logits[i * KS + j]);
            }
        }
    }

    // ---- butterfly-sum partials across the 4 sub-lanes of this pixel ----
    #pragma unroll
    for (int t49 = 0; t49 < KS * KS; ++t49) {
        float v = logits[t49];
        v += __shfl_xor(v, 1);
        v += __shfl_xor(v, 2);
        logits[t49] = v;        // identical on all 4 lanes of the quad
    }

    // ---- softmax over 49 taps (duplicated per lane; deterministic) ----
    {
        float m = logits[0];
        #pragma unroll
        for (int t49 = 1; t49 < KS * KS; ++t49) m = fmaxf(m, logits[t49]);
        float sum = 0.f;
        #pragma unroll
        for (int t49 = 0; t49 < KS * KS; ++t49) {
            const float e = __expf(logits[t49] - m);
            logits[t49] = e;
            sum += e;
        }
        const float inv = 1.f / sum;
        #pragma unroll
        for (int t49 = 0; t49 < KS * KS; ++t49) logits[t49] *= inv;
    }

    // ---- PV for this sub's 8 channels ----
    {
        const unsigned short* vp = vi + (plane * P2 + pos0) * 8;
        float a[8] = {};
        #pragma unroll
        for (int i = 0; i < KS; ++i) {
            const unsigned short* vr = vp + i * WP * 8;
            #pragma unroll
            for (int j = 0; j < KS; ++j) {
                const f16x8 vv = *(const f16x8*)(vr + j * 8);
                const float wt = logits[i * KS + j];
                #pragma unroll
                for (int c = 0; c < 8; ++c)
                    a[c] += wt * (float)vv[c];
            }
        }
        float* op = out + ((size_t)b * OUTC + g * CG + s * 8) * P1 + p;
        #pragma unroll
        for (int c = 0; c < 8; ++c)
            op[(size_t)c * P1] = a[c];
    }
}

extern "C" void kernel_launch(void* const* d_in, const int* in_sizes, int n_in,
                              void* d_out, int out_size, void* d_ws, size_t ws_size,
                              hipStream_t stream) {
    const float* fm = (const float*)d_in[0];
    const float* wq = (const float*)d_in[1];
    const float* wk = (const float*)d_in[2];
    const float* wv = (const float*)d_in[3];
    const float* rh = (const float*)d_in[4];
    const float* rw = (const float*)d_in[5];
    float* out = (float*)d_out;

    unsigned short* ws = (unsigned short*)d_ws;
    unsigned short* qi = ws;                             // 2*8*4*3136*8 fp16
    unsigned short* ki = qi + (size_t)B * OUTC * P1;     // 2*8*4*3844*8 fp16
    unsigned short* vi = ki + (size_t)B * OUTC * P2;

    gemm_kernel<<<dim3(31, 6, B), 256, 0, stream>>>(fm, wq, wk, wv, qi, ki, vi);
    attn_kernel<<<dim3(P1 * 4 / 256, G, B), 256, 0, stream>>>(qi, ki, vi, rh, rw, out);
}

// Round 3
// 121.056 us; speedup vs baseline: 1.0095x; 1.0095x over previous
//
#include <hip/hip_runtime.h>
#include <hip/hip_bf16.h>

// Problem constants
#define B    2
#define CIN  256
#define H    56
#define W    56
#define OUTC 256
#define KS   7
#define PAD  3
#define G    8
#define CG   32
#define HP   62           // H + 2*PAD
#define WP   62
#define P1   (H * W)      // 3136
#define P2   (HP * WP)    // 3844

typedef __attribute__((ext_vector_type(2))) _Float16 h2;
typedef __attribute__((ext_vector_type(8))) _Float16 f16x8;
typedef __attribute__((ext_vector_type(8))) unsigned short ushort8;
typedef __attribute__((ext_vector_type(4))) float f32x4;

__device__ inline unsigned short f2h(float f) {    // RNE float->fp16 bits
    const _Float16 h = (_Float16)f;
    return *(const unsigned short*)&h;
}

__device__ inline float fdot2(h2 a, h2 b, float c) {
#if defined(__has_builtin)
#if __has_builtin(__builtin_amdgcn_fdot2)
    return __builtin_amdgcn_fdot2(a, b, c, false);
#else
    return c + (float)a[0] * (float)b[0] + (float)a[1] * (float)b[1];
#endif
#else
    return c + (float)a[0] * (float)b[0] + (float)a[1] * (float)b[1];
#endif
}

__device__ inline float dot8(const f16x8 q, const f16x8 k, float s) {
    s = fdot2((h2){q[0], q[1]}, (h2){k[0], k[1]}, s);
    s = fdot2((h2){q[2], q[3]}, (h2){k[2], k[3]}, s);
    s = fdot2((h2){q[4], q[5]}, (h2){k[4], k[5]}, s);
    s = fdot2((h2){q[6], q[7]}, (h2){k[6], k[7]}, s);
    return s;
}

// ---------------------------------------------------------------------------
// Fused fp32->fp16 + MFMA GEMM (one launch): grid (31, 6, B).  (unchanged)
//   y<2  : q GEMM  (w_q x fm_t1), x<25 only (N=P1)
//   y>=2 : kv GEMM (w_k rows 0..255, w_v rows 256..511 x padded fm_t0, N=P2)
// 128x128 tile, 4 waves, BK=32; staging converts fp32 inputs inline.
// Epilogue writes fp16 INTERLEAVED planes: base[((b*8+g)*4+sub)*Pstr + n]*8+l8.
// ---------------------------------------------------------------------------
#define ASTR 40
__global__ __launch_bounds__(256, 2) void gemm_kernel(const float* __restrict__ fm,
                                                      const float* __restrict__ wq,
                                                      const float* __restrict__ wk,
                                                      const float* __restrict__ wv,
                                                      unsigned short* __restrict__ qi,
                                                      unsigned short* __restrict__ ki,
                                                      unsigned short* __restrict__ vi) {
    const int b = blockIdx.z;
    const bool isQ = blockIdx.y < 2;
    if (isQ && blockIdx.x >= 25) return;
    const int o0 = (isQ ? blockIdx.y : (blockIdx.y - 2)) * 128;   // 0..383
    const int n0 = blockIdx.x * 128;
    const int Nreal = isQ ? P1 : P2;
    const int Pstr  = isQ ? P1 : P2;

    const float* Wsrc;
    int orow0;
    if (isQ)            { Wsrc = wq; orow0 = o0; }
    else if (o0 < 256)  { Wsrc = wk; orow0 = o0; }
    else                { Wsrc = wv; orow0 = o0 - 256; }

    __shared__ unsigned short Alds[128 * ASTR];
    __shared__ unsigned short Blds[128 * ASTR];
    const int tid = threadIdx.x;
    const int lane = tid & 63;
    const int wave = tid >> 6;
    const int wr = (wave >> 1) * 64;
    const int wc = (wave & 1) * 64;
    const int lrow = lane & 15;
    const int quad = lane >> 4;

    const int arow = tid & 127;
    const int akc  = (tid >> 7) * 16;

    const int n = n0 + arow;
    int srcoff = -1;
    if (isQ) {
        if (n < P1) srcoff = n;
    } else {
        if (n < P2) {
            const int y = n / WP, x = n - y * WP;
            const int iy = y - PAD, ix = x - PAD;
            if (iy >= 0 && iy < H && ix >= 0 && ix < W) srcoff = iy * W + ix;
        }
    }
    const float* fmB = fm + ((size_t)b * (2 * CIN) + (isQ ? CIN : 0)) * P1;
    const float* wrow = Wsrc + (size_t)orow0 * CIN + (size_t)arow * CIN + akc;

    unsigned short* alp = Alds + arow * ASTR + akc;
    unsigned short* blp = Blds + arow * ASTR + akc;

    f32x4 acc[4][4] = {};

    float av[16], bv[16];
    {
        const float4 a0 = ((const float4*)wrow)[0];
        const float4 a1 = ((const float4*)wrow)[1];
        const float4 a2 = ((const float4*)wrow)[2];
        const float4 a3 = ((const float4*)wrow)[3];
        av[0]=a0.x; av[1]=a0.y; av[2]=a0.z; av[3]=a0.w;
        av[4]=a1.x; av[5]=a1.y; av[6]=a1.z; av[7]=a1.w;
        av[8]=a2.x; av[9]=a2.y; av[10]=a2.z; av[11]=a2.w;
        av[12]=a3.x; av[13]=a3.y; av[14]=a3.z; av[15]=a3.w;
        #pragma unroll
        for (int j = 0; j < 16; ++j)
            bv[j] = (srcoff >= 0) ? fmB[(size_t)(akc + j) * P1 + srcoff] : 0.f;
    }

    for (int kb = 0; kb < CIN / 32; ++kb) {
        {
            f16x8 p0, p1, p2, p3;
            #pragma unroll
            for (int j = 0; j < 8; ++j) {
                p0[j] = (_Float16)av[j];
                p1[j] = (_Float16)av[8 + j];
                p2[j] = (_Float16)bv[j];
                p3[j] = (_Float16)bv[8 + j];
            }
            *(f16x8*)(alp)     = p0;
            *(f16x8*)(alp + 8) = p1;
            *(f16x8*)(blp)     = p2;
            *(f16x8*)(blp + 8) = p3;
        }
        __syncthreads();
        if (kb < CIN / 32 - 1) {
            const int c0 = (kb + 1) * 32 + akc;
            const float* wnext = wrow + (kb + 1) * 32;
            const float4 a0 = ((const float4*)wnext)[0];
            const float4 a1 = ((const float4*)wnext)[1];
            const float4 a2 = ((const float4*)wnext)[2];
            const float4 a3 = ((const float4*)wnext)[3];
            av[0]=a0.x; av[1]=a0.y; av[2]=a0.z; av[3]=a0.w;
            av[4]=a1.x; av[5]=a1.y; av[6]=a1.z; av[7]=a1.w;
            av[8]=a2.x; av[9]=a2.y; av[10]=a2.z; av[11]=a2.w;
            av[12]=a3.x; av[13]=a3.y; av[14]=a3.z; av[15]=a3.w;
            #pragma unroll
            for (int j = 0; j < 16; ++j)
                bv[j] = (srcoff >= 0) ? fmB[(size_t)(c0 + j) * P1 + srcoff] : 0.f;
        }
        f16x8 af[4], bfr[4];
        #pragma unroll
        for (int mi = 0; mi < 4; ++mi)
            af[mi] = *(const f16x8*)&Alds[(wr + mi * 16 + lrow) * ASTR + quad * 8];
        #pragma unroll
        for (int ni = 0; ni < 4; ++ni)
            bfr[ni] = *(const f16x8*)&Blds[(wc + ni * 16 + lrow) * ASTR + quad * 8];
        #pragma unroll
        for (int mi = 0; mi < 4; ++mi)
            #pragma unroll
            for (int ni = 0; ni < 4; ++ni)
                acc[mi][ni] = __builtin_amdgcn_mfma_f32_16x16x32_f16(af[mi], bfr[ni], acc[mi][ni], 0, 0, 0);
        __syncthreads();
    }

    #pragma unroll
    for (int mi = 0; mi < 4; ++mi) {
        const int gmBase = o0 + wr + mi * 16 + quad * 4;
        int ch0;
        unsigned short* base;
        if (isQ)               { ch0 = gmBase;       base = qi; }
        else if (gmBase < 256) { ch0 = gmBase;       base = ki; }
        else                   { ch0 = gmBase - 256; base = vi; }
        const int g   = ch0 >> 5;
        const int sub = (ch0 >> 3) & 3;
        const int l8  = ch0 & 7;
        unsigned short* pbase = base + ((((size_t)b * 8 + g) * 4 + sub) * Pstr) * 8 + l8;
        #pragma unroll
        for (int ni = 0; ni < 4; ++ni) {
            const int gn = n0 + wc + ni * 16 + lrow;
            if (gn < Nreal) {
                ushort4 pk;
                pk.x = f2h(acc[mi][ni][0]);
                pk.y = f2h(acc[mi][ni][1]);
                pk.z = f2h(acc[mi][ni][2]);
                pk.w = f2h(acc[mi][ni][3]);
                *(ushort4*)(pbase + (size_t)gn * 8) = pk;
            }
        }
    }
}

// ---------------------------------------------------------------------------
// Grouped 7x7 attention v5: v4 compute + XCD-affine block mapping.
// Per (b,g) the K+V working set is 2*4*P2*16B ~= 0.98 MB; 16 (b,g) pairs
// over 8 XCDs = ~2.4 MB/XCD incl. q -> fits one XCD's 4 MiB L2.
// Flat grid of 784 blocks; decode g = flat&7, b = (flat>>3)&1, x = flat>>4.
// All blocks with equal g have flat == g (mod 8), so the round-robin
// dispatcher pins each (g)'s 98 blocks (both b) to ONE XCD -> the 49x
// window re-reads become local-L2 hits instead of cross-die L3 round trips.
// Thread = (pixel, sub): partial QK over 8 ch, 2-step __shfl_xor butterfly
// sums sub-partials, duplicated softmax, PV split by sub. No LDS/barriers.
// ---------------------------------------------------------------------------
__global__ __launch_bounds__(256) void attn_kernel(const unsigned short* __restrict__ qi,
                                                   const unsigned short* __restrict__ ki,
                                                   const unsigned short* __restrict__ vi,
                                                   const float* __restrict__ rel_h,
                                                   const float* __restrict__ rel_w,
                                                   float* __restrict__ out) {
    const int flat = blockIdx.x;                    // 0..783
    const int g = flat & 7;                         // XCD-affine group id
    const int b = (flat >> 3) & 1;
    const int t = (flat >> 4) * 256 + threadIdx.x;  // 0..12543
    const int s = t & 3;                            // sub-plane 0..3
    const int p = t >> 2;                           // pixel 0..3135

    const int h = p / W;
    const int w = p - h * W;
    const int pos0 = h * WP + w;                    // window origin in padded grid
    const size_t plane = ((size_t)b * G + g) * 4 + s;

    // ---- load this sub's 8 q channels ----
    const f16x8 q = *(const f16x8*)(qi + (plane * P1 + p) * 8);

    // ---- partial bias over this sub's 8 channels (rel uniform -> SGPR) ----
    const float* rel = (g < 4) ? (rel_h + (size_t)g * CG * KS)
                               : (rel_w + (size_t)(g - 4) * CG * KS);
    float bd[KS];
    #pragma unroll
    for (int t7 = 0; t7 < KS; ++t7) {
        float s0 = 0.f;
        #pragma unroll
        for (int j = 0; j < 8; ++j)
            s0 += (float)q[j] * rel[(s * 8 + j) * KS + t7];
        bd[t7] = s0;
    }

    float logits[KS * KS];
    #pragma unroll
    for (int i = 0; i < KS; ++i)
        #pragma unroll
        for (int j = 0; j < KS; ++j)
            logits[i * KS + j] = (g < 4) ? bd[i] : bd[j];

    // ---- partial QK^T over this sub: 49 taps ----
    {
        const unsigned short* kp = ki + (plane * P2 + pos0) * 8;
        #pragma unroll
        for (int i = 0; i < KS; ++i) {
            const unsigned short* kr = kp + i * WP * 8;
            #pragma unroll
            for (int j = 0; j < KS; ++j) {
                const f16x8 kv = *(const f16x8*)(kr + j * 8);
                logits[i * KS + j] = dot8(q, kv, logits[i * KS + j]);
            }
        }
    }

    // ---- butterfly-sum partials across the 4 sub-lanes of this pixel ----
    #pragma unroll
    for (int t49 = 0; t49 < KS * KS; ++t49) {
        float v = logits[t49];
        v += __shfl_xor(v, 1);
        v += __shfl_xor(v, 2);
        logits[t49] = v;        // identical on all 4 lanes of the quad
    }

    // ---- softmax over 49 taps (duplicated per lane; deterministic) ----
    {
        float m = logits[0];
        #pragma unroll
        for (int t49 = 1; t49 < KS * KS; ++t49) m = fmaxf(m, logits[t49]);
        float sum = 0.f;
        #pragma unroll
        for (int t49 = 0; t49 < KS * KS; ++t49) {
            const float e = __expf(logits[t49] - m);
            logits[t49] = e;
            sum += e;
        }
        const float inv = 1.f / sum;
        #pragma unroll
        for (int t49 = 0; t49 < KS * KS; ++t49) logits[t49] *= inv;
    }

    // ---- PV for this sub's 8 channels ----
    {
        const unsigned short* vp = vi + (plane * P2 + pos0) * 8;
        float a[8] = {};
        #pragma unroll
        for (int i = 0; i < KS; ++i) {
            const unsigned short* vr = vp + i * WP * 8;
            #pragma unroll
            for (int j = 0; j < KS; ++j) {
                const f16x8 vv = *(const f16x8*)(vr + j * 8);
                const float wt = logits[i * KS + j];
                #pragma unroll
                for (int c = 0; c < 8; ++c)
                    a[c] += wt * (float)vv[c];
            }
        }
        float* op = out + ((size_t)b * OUTC + g * CG + s * 8) * P1 + p;
        #pragma unroll
        for (int c = 0; c < 8; ++c)
            op[(size_t)c * P1] = a[c];
    }
}

extern "C" void kernel_launch(void* const* d_in, const int* in_sizes, int n_in,
                              void* d_out, int out_size, void* d_ws, size_t ws_size,
                              hipStream_t stream) {
    const float* fm = (const float*)d_in[0];
    const float* wq = (const float*)d_in[1];
    const float* wk = (const float*)d_in[2];
    const float* wv = (const float*)d_in[3];
    const float* rh = (const float*)d_in[4];
    const float* rw = (const float*)d_in[5];
    float* out = (float*)d_out;

    unsigned short* ws = (unsigned short*)d_ws;
    unsigned short* qi = ws;                             // 2*8*4*3136*8 fp16
    unsigned short* ki = qi + (size_t)B * OUTC * P1;     // 2*8*4*3844*8 fp16
    unsigned short* vi = ki + (size_t)B * OUTC * P2;

    gemm_kernel<<<dim3(31, 6, B), 256, 0, stream>>>(fm, wq, wk, wv, qi, ki, vi);
    attn_kernel<<<dim3(16 * 49, 1, 1), 256, 0, stream>>>(qi, ki, vi, rh, rw, out);
}

// Round 4
// 114.697 us; speedup vs baseline: 1.0655x; 1.0554x over previous
//
#include <hip/hip_runtime.h>
#include <hip/hip_bf16.h>

// Problem constants
#define B    2
#define CIN  256
#define H    56
#define W    56
#define OUTC 256
#define KS   7
#define PAD  3
#define G    8
#define CG   32
#define HP   62           // H + 2*PAD
#define WP   62
#define P1   (H * W)      // 3136
#define P2   (HP * WP)    // 3844

typedef __attribute__((ext_vector_type(2))) _Float16 h2;
typedef __attribute__((ext_vector_type(8))) _Float16 f16x8;
typedef __attribute__((ext_vector_type(8))) unsigned short ushort8;
typedef __attribute__((ext_vector_type(4))) float f32x4;

__device__ inline unsigned short f2h(float f) {    // RNE float->fp16 bits
    const _Float16 h = (_Float16)f;
    return *(const unsigned short*)&h;
}

__device__ inline float fdot2(h2 a, h2 b, float c) {
#if defined(__has_builtin)
#if __has_builtin(__builtin_amdgcn_fdot2)
    return __builtin_amdgcn_fdot2(a, b, c, false);
#else
    return c + (float)a[0] * (float)b[0] + (float)a[1] * (float)b[1];
#endif
#else
    return c + (float)a[0] * (float)b[0] + (float)a[1] * (float)b[1];
#endif
}

__device__ inline float dot8(const f16x8 q, const f16x8 k, float s) {
    s = fdot2((h2){q[0], q[1]}, (h2){k[0], k[1]}, s);
    s = fdot2((h2){q[2], q[3]}, (h2){k[2], k[3]}, s);
    s = fdot2((h2){q[4], q[5]}, (h2){k[4], k[5]}, s);
    s = fdot2((h2){q[6], q[7]}, (h2){k[6], k[7]}, s);
    return s;
}

// ---------------------------------------------------------------------------
// Fused fp32->fp16 + MFMA GEMM: grid (31, 6, B).
//   y<2  : q GEMM  (w_q x fm_t1), x<25 only (N=P1)
//   y>=2 : kv GEMM (w_k rows 0..255, w_v rows 256..511 x padded fm_t0, N=P2)
// 128x128 tile, 4 waves, BK=32; staging converts fp32 inputs inline.
// v2: DOUBLE-BUFFERED LDS -> one barrier per K-step (was two). Buffer k%2
// is rewritten two barriers after its readers drained (compiler emits
// lgkmcnt(0) before s_barrier), so a single barrier/iter is race-free.
// LDS 41 KB -> 3 blocks/CU co-resident (was 2) for cross-block overlap.
// Epilogue writes fp16 INTERLEAVED planes: base[((b*8+g)*4+sub)*Pstr + n]*8+l8.
// ---------------------------------------------------------------------------
#define ASTR 40
__global__ __launch_bounds__(256, 2) void gemm_kernel(const float* __restrict__ fm,
                                                      const float* __restrict__ wq,
                                                      const float* __restrict__ wk,
                                                      const float* __restrict__ wv,
                                                      unsigned short* __restrict__ qi,
                                                      unsigned short* __restrict__ ki,
                                                      unsigned short* __restrict__ vi) {
    const int b = blockIdx.z;
    const bool isQ = blockIdx.y < 2;
    if (isQ && blockIdx.x >= 25) return;
    const int o0 = (isQ ? blockIdx.y : (blockIdx.y - 2)) * 128;   // 0..383
    const int n0 = blockIdx.x * 128;
    const int Nreal = isQ ? P1 : P2;
    const int Pstr  = isQ ? P1 : P2;

    const float* Wsrc;
    int orow0;
    if (isQ)            { Wsrc = wq; orow0 = o0; }
    else if (o0 < 256)  { Wsrc = wk; orow0 = o0; }
    else                { Wsrc = wv; orow0 = o0 - 256; }

    __shared__ unsigned short Alds[2][128 * ASTR];
    __shared__ unsigned short Blds[2][128 * ASTR];
    const int tid = threadIdx.x;
    const int lane = tid & 63;
    const int wave = tid >> 6;
    const int wr = (wave >> 1) * 64;
    const int wc = (wave & 1) * 64;
    const int lrow = lane & 15;
    const int quad = lane >> 4;

    const int arow = tid & 127;
    const int akc  = (tid >> 7) * 16;

    const int n = n0 + arow;
    int srcoff = -1;
    if (isQ) {
        if (n < P1) srcoff = n;
    } else {
        if (n < P2) {
            const int y = n / WP, x = n - y * WP;
            const int iy = y - PAD, ix = x - PAD;
            if (iy >= 0 && iy < H && ix >= 0 && ix < W) srcoff = iy * W + ix;
        }
    }
    const float* fmB = fm + ((size_t)b * (2 * CIN) + (isQ ? CIN : 0)) * P1;
    const float* wrow = Wsrc + (size_t)orow0 * CIN + (size_t)arow * CIN + akc;

    f32x4 acc[4][4] = {};

    float av[16], bv[16];
    {
        const float4 a0 = ((const float4*)wrow)[0];
        const float4 a1 = ((const float4*)wrow)[1];
        const float4 a2 = ((const float4*)wrow)[2];
        const float4 a3 = ((const float4*)wrow)[3];
        av[0]=a0.x; av[1]=a0.y; av[2]=a0.z; av[3]=a0.w;
        av[4]=a1.x; av[5]=a1.y; av[6]=a1.z; av[7]=a1.w;
        av[8]=a2.x; av[9]=a2.y; av[10]=a2.z; av[11]=a2.w;
        av[12]=a3.x; av[13]=a3.y; av[14]=a3.z; av[15]=a3.w;
        #pragma unroll
        for (int j = 0; j < 16; ++j)
            bv[j] = (srcoff >= 0) ? fmB[(size_t)(akc + j) * P1 + srcoff] : 0.f;
    }

    for (int kb = 0; kb < CIN / 32; ++kb) {
        const int cur = kb & 1;
        unsigned short* alp = Alds[cur] + arow * ASTR + akc;
        unsigned short* blp = Blds[cur] + arow * ASTR + akc;
        {
            f16x8 p0, p1, p2, p3;
            #pragma unroll
            for (int j = 0; j < 8; ++j) {
                p0[j] = (_Float16)av[j];
                p1[j] = (_Float16)av[8 + j];
                p2[j] = (_Float16)bv[j];
                p3[j] = (_Float16)bv[8 + j];
            }
            *(f16x8*)(alp)     = p0;
            *(f16x8*)(alp + 8) = p1;
            *(f16x8*)(blp)     = p2;
            *(f16x8*)(blp + 8) = p3;
        }
        __syncthreads();                    // buf[cur] staged; no trailing barrier
        if (kb < CIN / 32 - 1) {
            const int c0 = (kb + 1) * 32 + akc;
            const float* wnext = wrow + (kb + 1) * 32;
            const float4 a0 = ((const float4*)wnext)[0];
            const float4 a1 = ((const float4*)wnext)[1];
            const float4 a2 = ((const float4*)wnext)[2];
            const float4 a3 = ((const float4*)wnext)[3];
            av[0]=a0.x; av[1]=a0.y; av[2]=a0.z; av[3]=a0.w;
            av[4]=a1.x; av[5]=a1.y; av[6]=a1.z; av[7]=a1.w;
            av[8]=a2.x; av[9]=a2.y; av[10]=a2.z; av[11]=a2.w;
            av[12]=a3.x; av[13]=a3.y; av[14]=a3.z; av[15]=a3.w;
            #pragma unroll
            for (int j = 0; j < 16; ++j)
                bv[j] = (srcoff >= 0) ? fmB[(size_t)(c0 + j) * P1 + srcoff] : 0.f;
        }
        f16x8 af[4], bfr[4];
        #pragma unroll
        for (int mi = 0; mi < 4; ++mi)
            af[mi] = *(const f16x8*)&Alds[cur][(wr + mi * 16 + lrow) * ASTR + quad * 8];
        #pragma unroll
        for (int ni = 0; ni < 4; ++ni)
            bfr[ni] = *(const f16x8*)&Blds[cur][(wc + ni * 16 + lrow) * ASTR + quad * 8];
        #pragma unroll
        for (int mi = 0; mi < 4; ++mi)
            #pragma unroll
            for (int ni = 0; ni < 4; ++ni)
                acc[mi][ni] = __builtin_amdgcn_mfma_f32_16x16x32_f16(af[mi], bfr[ni], acc[mi][ni], 0, 0, 0);
    }

    #pragma unroll
    for (int mi = 0; mi < 4; ++mi) {
        const int gmBase = o0 + wr + mi * 16 + quad * 4;
        int ch0;
        unsigned short* base;
        if (isQ)               { ch0 = gmBase;       base = qi; }
        else if (gmBase < 256) { ch0 = gmBase;       base = ki; }
        else                   { ch0 = gmBase - 256; base = vi; }
        const int g   = ch0 >> 5;
        const int sub = (ch0 >> 3) & 3;
        const int l8  = ch0 & 7;
        unsigned short* pbase = base + ((((size_t)b * 8 + g) * 4 + sub) * Pstr) * 8 + l8;
        #pragma unroll
        for (int ni = 0; ni < 4; ++ni) {
            const int gn = n0 + wc + ni * 16 + lrow;
            if (gn < Nreal) {
                ushort4 pk;
                pk.x = f2h(acc[mi][ni][0]);
                pk.y = f2h(acc[mi][ni][1]);
                pk.z = f2h(acc[mi][ni][2]);
                pk.w = f2h(acc[mi][ni][3]);
                *(ushort4*)(pbase + (size_t)gn * 8) = pk;
            }
        }
    }
}

// ---------------------------------------------------------------------------
// Grouped 7x7 attention v3 (reverted: measured-best structure).
// Barrier-free, LDS-free, one thread per pixel; K/V windows read directly
// from global (L1/L2-resident); 49 independent accum chains for ILP/MLP.
// Grid: (13, G, B), 256-thread blocks.
// ---------------------------------------------------------------------------
__global__ __launch_bounds__(256) void attn_kernel(const unsigned short* __restrict__ qi,
                                                   const unsigned short* __restrict__ ki,
                                                   const unsigned short* __restrict__ vi,
                                                   const float* __restrict__ rel_h,
                                                   const float* __restrict__ rel_w,
                                                   float* __restrict__ out) {
    const int b = blockIdx.z;
    const int g = blockIdx.y;
    const int tid = threadIdx.x;

    int p = blockIdx.x * 256 + tid;
    const bool act = p < P1;
    if (!act) p = P1 - 1;              // clamp: loads stay in-bounds, stores skipped

    const int h = p / W;
    const int w = p - h * W;
    const int pos0 = h * WP + w;       // window origin in padded 62x62 grid
    const size_t bg4 = ((size_t)b * G + g) * 4;

    // ---- load q (32 channels as 4x f16x8) ----
    f16x8 qh[4];
    #pragma unroll
    for (int s = 0; s < 4; ++s)
        qh[s] = *(const f16x8*)(qi + ((bg4 + s) * P1 + p) * 8);

    // ---- bias: bd[t] = sum_c q[c] * rel[c,t]  (rel is uniform -> SGPR) ----
    const float* rel = (g < 4) ? (rel_h + (size_t)g * CG * KS)
                               : (rel_w + (size_t)(g - 4) * CG * KS);
    float bd[KS];
    #pragma unroll
    for (int t = 0; t < KS; ++t) {
        float s0 = 0.f;
        #pragma unroll
        for (int s = 0; s < 4; ++s)
            #pragma unroll
            for (int j = 0; j < 8; ++j)
                s0 += (float)qh[s][j] * rel[(s * 8 + j) * KS + t];
        bd[t] = s0;
    }

    float logits[KS * KS];
    #pragma unroll
    for (int i = 0; i < KS; ++i)
        #pragma unroll
        for (int j = 0; j < KS; ++j)
            logits[i * KS + j] = (g < 4) ? bd[i] : bd[j];

    // ---- QK^T: 4 subs x 49 taps, direct global reads (L1/L2 hits) ----
    #pragma unroll
    for (int s = 0; s < 4; ++s) {
        const unsigned short* kp = ki + ((bg4 + s) * P2 + pos0) * 8;
        const f16x8 q = qh[s];
        #pragma unroll
        for (int i = 0; i < KS; ++i) {
            const unsigned short* kr = kp + i * WP * 8;
            #pragma unroll
            for (int j = 0; j < KS; ++j) {
                const f16x8 kv = *(const f16x8*)(kr + j * 8);
                logits[i * KS + j] = dot8(q, kv, logits[i * KS + j]);
            }
        }
    }

    // ---- softmax over 49 taps ----
    {
        float m = logits[0];
        #pragma unroll
        for (int t = 1; t < KS * KS; ++t) m = fmaxf(m, logits[t]);
        float sum = 0.f;
        #pragma unroll
        for (int t = 0; t < KS * KS; ++t) {
            const float e = __expf(logits[t] - m);
            logits[t] = e;
            sum += e;
        }
        const float inv = 1.f / sum;
        #pragma unroll
        for (int t = 0; t < KS * KS; ++t) logits[t] *= inv;
    }

    // ---- PV: per sub, 8-channel fp32 accumulate (v_fma_mix), then store ----
    #pragma unroll
    for (int s = 0; s < 4; ++s) {
        const unsigned short* vp = vi + ((bg4 + s) * P2 + pos0) * 8;
        float a[8] = {};
        #pragma unroll
        for (int i = 0; i < KS; ++i) {
            const unsigned short* vr = vp + i * WP * 8;
            #pragma unroll
            for (int j = 0; j < KS; ++j) {
                const f16x8 vv = *(const f16x8*)(vr + j * 8);
                const float wt = logits[i * KS + j];
                #pragma unroll
                for (int c = 0; c < 8; ++c)
                    a[c] += wt * (float)vv[c];
            }
        }
        if (act) {
            float* op = out + ((size_t)b * OUTC + g * CG + s * 8) * P1 + p;
            #pragma unroll
            for (int c = 0; c < 8; ++c)
                op[(size_t)c * P1] = a[c];
        }
    }
}

extern "C" void kernel_launch(void* const* d_in, const int* in_sizes, int n_in,
                              void* d_out, int out_size, void* d_ws, size_t ws_size,
                              hipStream_t stream) {
    const float* fm = (const float*)d_in[0];
    const float* wq = (const float*)d_in[1];
    const float* wk = (const float*)d_in[2];
    const float* wv = (const float*)d_in[3];
    const float* rh = (const float*)d_in[4];
    const float* rw = (const float*)d_in[5];
    float* out = (float*)d_out;

    unsigned short* ws = (unsigned short*)d_ws;
    unsigned short* qi = ws;                             // 2*8*4*3136*8 fp16
    unsigned short* ki = qi + (size_t)B * OUTC * P1;     // 2*8*4*3844*8 fp16
    unsigned short* vi = ki + (size_t)B * OUTC * P2;

    gemm_kernel<<<dim3(31, 6, B), 256, 0, stream>>>(fm, wq, wk, wv, qi, ki, vi);
    attn_kernel<<<dim3((P1 + 255) / 256, G, B), 256, 0, stream>>>(qi, ki, vi, rh, rw, out);
}

// Round 6
// 113.326 us; speedup vs baseline: 1.0784x; 1.0121x over previous
//
#include <hip/hip_runtime.h>
#include <hip/hip_bf16.h>

// Problem constants
#define B    2
#define CIN  256
#define H    56
#define W    56
#define OUTC 256
#define KS   7
#define PAD  3
#define G    8
#define CG   32
#define HP   62           // H + 2*PAD
#define WP   62
#define P1   (H * W)      // 3136
#define P2   (HP * WP)    // 3844

typedef __attribute__((ext_vector_type(2))) _Float16 h2;
typedef __attribute__((ext_vector_type(8))) _Float16 f16x8;
typedef __attribute__((ext_vector_type(4))) float f32x4;

__device__ inline unsigned short f2h(float f) {    // RNE float->fp16 bits
    const _Float16 h = (_Float16)f;
    return *(const unsigned short*)&h;
}

__device__ inline float fdot2(h2 a, h2 b, float c) {
#if defined(__has_builtin)
#if __has_builtin(__builtin_amdgcn_fdot2)
    return __builtin_amdgcn_fdot2(a, b, c, false);
#else
    return c + (float)a[0] * (float)b[0] + (float)a[1] * (float)b[1];
#endif
#else
    return c + (float)a[0] * (float)b[0] + (float)a[1] * (float)b[1];
#endif
}

__device__ inline float dot8(const f16x8 q, const f16x8 k, float s) {
    s = fdot2((h2){q[0], q[1]}, (h2){k[0], k[1]}, s);
    s = fdot2((h2){q[2], q[3]}, (h2){k[2], k[3]}, s);
    s = fdot2((h2){q[4], q[5]}, (h2){k[4], k[5]}, s);
    s = fdot2((h2){q[6], q[7]}, (h2){k[6], k[7]}, s);
    return s;
}

// ---------------------------------------------------------------------------
// Fused fp32->fp16 + MFMA GEMM: grid (31, 6, B).
//   y<2  : q GEMM  (w_q x fm_t1), x<25 only (N=P1)
//   y>=2 : kv GEMM (w_k rows 0..255, w_v rows 256..511 x padded fm_t0, N=P2)
// 128x128 tile, 4 waves, BK=32; staging converts fp32 inputs inline.
// Double-buffered LDS -> one barrier per K-step (measured ~neutral vs
// single-buffer, kept for fewer barrier drains).
// Epilogue writes fp16 INTERLEAVED planes: base[((b*8+g)*4+sub)*Pstr+n]*8+l8.
// ---------------------------------------------------------------------------
#define ASTR 40
__global__ __launch_bounds__(256, 2) void gemm_kernel(const float* __restrict__ fm,
                                                      const float* __restrict__ wq,
                                                      const float* __restrict__ wk,
                                                      const float* __restrict__ wv,
                                                      unsigned short* __restrict__ qi,
                                                      unsigned short* __restrict__ ki,
                                                      unsigned short* __restrict__ vi) {
    const int b = blockIdx.z;
    const bool isQ = blockIdx.y < 2;
    if (isQ && blockIdx.x >= 25) return;
    const int o0 = (isQ ? blockIdx.y : (blockIdx.y - 2)) * 128;   // 0..383
    const int n0 = blockIdx.x * 128;
    const int Nreal = isQ ? P1 : P2;
    const int Pstr  = isQ ? P1 : P2;

    const float* Wsrc;
    int orow0;
    if (isQ)            { Wsrc = wq; orow0 = o0; }
    else if (o0 < 256)  { Wsrc = wk; orow0 = o0; }
    else                { Wsrc = wv; orow0 = o0 - 256; }

    __shared__ unsigned short Alds[2][128 * ASTR];
    __shared__ unsigned short Blds[2][128 * ASTR];
    const int tid = threadIdx.x;
    const int lane = tid & 63;
    const int wave = tid >> 6;
    const int wr = (wave >> 1) * 64;
    const int wc = (wave & 1) * 64;
    const int lrow = lane & 15;
    const int quad = lane >> 4;

    const int arow = tid & 127;
    const int akc  = (tid >> 7) * 16;

    const int n = n0 + arow;
    int srcoff = -1;
    if (isQ) {
        if (n < P1) srcoff = n;
    } else {
        if (n < P2) {
            const int y = n / WP, x = n - y * WP;
            const int iy = y - PAD, ix = x - PAD;
            if (iy >= 0 && iy < H && ix >= 0 && ix < W) srcoff = iy * W + ix;
        }
    }
    const float* fmB = fm + ((size_t)b * (2 * CIN) + (isQ ? CIN : 0)) * P1;
    const float* wrow = Wsrc + (size_t)orow0 * CIN + (size_t)arow * CIN + akc;

    f32x4 acc[4][4] = {};

    float av[16], bv[16];
    {
        const float4 a0 = ((const float4*)wrow)[0];
        const float4 a1 = ((const float4*)wrow)[1];
        const float4 a2 = ((const float4*)wrow)[2];
        const float4 a3 = ((const float4*)wrow)[3];
        av[0]=a0.x; av[1]=a0.y; av[2]=a0.z; av[3]=a0.w;
        av[4]=a1.x; av[5]=a1.y; av[6]=a1.z; av[7]=a1.w;
        av[8]=a2.x; av[9]=a2.y; av[10]=a2.z; av[11]=a2.w;
        av[12]=a3.x; av[13]=a3.y; av[14]=a3.z; av[15]=a3.w;
        #pragma unroll
        for (int j = 0; j < 16; ++j)
            bv[j] = (srcoff >= 0) ? fmB[(size_t)(akc + j) * P1 + srcoff] : 0.f;
    }

    for (int kb = 0; kb < CIN / 32; ++kb) {
        const int cur = kb & 1;
        unsigned short* alp = Alds[cur] + arow * ASTR + akc;
        unsigned short* blp = Blds[cur] + arow * ASTR + akc;
        {
            f16x8 p0, p1, p2, p3;
            #pragma unroll
            for (int j = 0; j < 8; ++j) {
                p0[j] = (_Float16)av[j];
                p1[j] = (_Float16)av[8 + j];
                p2[j] = (_Float16)bv[j];
                p3[j] = (_Float16)bv[8 + j];
            }
            *(f16x8*)(alp)     = p0;
            *(f16x8*)(alp + 8) = p1;
            *(f16x8*)(blp)     = p2;
            *(f16x8*)(blp + 8) = p3;
        }
        __syncthreads();                    // buf[cur] staged; one barrier/step
        if (kb < CIN / 32 - 1) {
            const int c0 = (kb + 1) * 32 + akc;
            const float* wnext = wrow + (kb + 1) * 32;
            const float4 a0 = ((const float4*)wnext)[0];
            const float4 a1 = ((const float4*)wnext)[1];
            const float4 a2 = ((const float4*)wnext)[2];
            const float4 a3 = ((const float4*)wnext)[3];
            av[0]=a0.x; av[1]=a0.y; av[2]=a0.z; av[3]=a0.w;
            av[4]=a1.x; av[5]=a1.y; av[6]=a1.z; av[7]=a1.w;
            av[8]=a2.x; av[9]=a2.y; av[10]=a2.z; av[11]=a2.w;
            av[12]=a3.x; av[13]=a3.y; av[14]=a3.z; av[15]=a3.w;
            #pragma unroll
            for (int j = 0; j < 16; ++j)
                bv[j] = (srcoff >= 0) ? fmB[(size_t)(c0 + j) * P1 + srcoff] : 0.f;
        }
        f16x8 af[4], bfr[4];
        #pragma unroll
        for (int mi = 0; mi < 4; ++mi)
            af[mi] = *(const f16x8*)&Alds[cur][(wr + mi * 16 + lrow) * ASTR + quad * 8];
        #pragma unroll
        for (int ni = 0; ni < 4; ++ni)
            bfr[ni] = *(const f16x8*)&Blds[cur][(wc + ni * 16 + lrow) * ASTR + quad * 8];
        #pragma unroll
        for (int mi = 0; mi < 4; ++mi)
            #pragma unroll
            for (int ni = 0; ni < 4; ++ni)
                acc[mi][ni] = __builtin_amdgcn_mfma_f32_16x16x32_f16(af[mi], bfr[ni], acc[mi][ni], 0, 0, 0);
    }

    #pragma unroll
    for (int mi = 0; mi < 4; ++mi) {
        const int gmBase = o0 + wr + mi * 16 + quad * 4;
        int ch0;
        unsigned short* base;
        if (isQ)               { ch0 = gmBase;       base = qi; }
        else if (gmBase < 256) { ch0 = gmBase;       base = ki; }
        else                   { ch0 = gmBase - 256; base = vi; }
        const int g   = ch0 >> 5;
        const int sub = (ch0 >> 3) & 3;
        const int l8  = ch0 & 7;
        unsigned short* pbase = base + ((((size_t)b * 8 + g) * 4 + sub) * Pstr) * 8 + l8;
        #pragma unroll
        for (int ni = 0; ni < 4; ++ni) {
            const int gn = n0 + wc + ni * 16 + lrow;
            if (gn < Nreal) {
                ushort4 pk;
                pk.x = f2h(acc[mi][ni][0]);
                pk.y = f2h(acc[mi][ni][1]);
                pk.z = f2h(acc[mi][ni][2]);
                pk.w = f2h(acc[mi][ni][3]);
                *(ushort4*)(pbase + (size_t)gn * 8) = pk;
            }
        }
    }
}

// ---------------------------------------------------------------------------
// Grouped 7x7 attention (R0 measured-best structure, wide staging):
// Block = 4 pixel rows x 56 cols for one (b,g): 256 threads, 112
// compute-active (rp = tid/56 selects row pair r0+2rp, r0+2rp+1; cx=tid%56).
// ALL 256 threads stage: 5 iters/phase (vs 10 at 128 thr) -> staging load
// chain halves; staging latency was the dominant term.
// Window = 10 padded rows x 62 = 620 pos; halves of 16 ch (2 f16x8 subs).
// LDS: f16x8 sbuf[2 halves][2 subs x 620] = 39,680 B.
// Read sharing: per tap-col j, 8 row-reads (ii=0..7) serve pixel0 taps ii<7
// and pixel1 taps ii>=1 -> 1.75x fewer ds_read_b128 per output; lane stride
// 16 B (conflict-free). 4-barrier K/V channel-split pipeline as R0.
// ---------------------------------------------------------------------------
#define NPOS4 620    // 10 * 62
#define HALFE 1240   // 2 subs * 620
__global__ __launch_bounds__(256) void attn_kernel(const unsigned short* __restrict__ qi,
                                                   const unsigned short* __restrict__ ki,
                                                   const unsigned short* __restrict__ vi,
                                                   const float* __restrict__ rel_h,
                                                   const float* __restrict__ rel_w,
                                                   float* __restrict__ out) {
    __shared__ f16x8 sbuf[2 * HALFE];   // 39,680 B

    const int b  = blockIdx.z;
    const int g  = blockIdx.y;
    const int r0 = blockIdx.x * 4;      // first pixel row of 4-row strip
    const int oc0 = g * CG;
    const int tid = threadIdx.x;
    const bool active = tid < 112;
    const int rp = tid / 56;            // 0..1 row-pair in strip (for tid<112)
    const int cx = tid - rp * 56;       // 0..55
    const int pr0 = r0 + 2 * rp;        // pixel rows pr0, pr0+1
    const int pix0 = pr0 * W + cx;
    const int pix1 = pix0 + W;

    const size_t bg4 = ((size_t)b * 8 + g) * 4;
    const size_t rowoff8 = ((size_t)r0 * WP) * 8;

    f16x8* bufA = sbuf;
    f16x8* bufB = sbuf + HALFE;

    // q for both pixels (issued before staging barrier)
    f16x8 qh0[4], qh1[4];
    if (active) {
        #pragma unroll
        for (int sub = 0; sub < 4; ++sub) {
            qh0[sub] = *(const f16x8*)(qi + ((bg4 + sub) * P1 + pix0) * 8);
            qh1[sub] = *(const f16x8*)(qi + ((bg4 + sub) * P1 + pix1) * 8);
        }
    }

    f16x8 st[5];
    // ---- stage K half A (subs 0,1): all 256 threads ----
    {
        const unsigned short* gb = ki + bg4 * P2 * 8 + rowoff8;
        #pragma unroll
        for (int it = 0; it < 5; ++it) {
            const int e = tid + it * 256;
            if (e < HALFE) {
                const int sl = (e >= NPOS4);
                const int pos = e - (sl ? NPOS4 : 0);
                st[it] = *(const f16x8*)(gb + ((size_t)sl * P2 + pos) * 8);
            }
        }
        #pragma unroll
        for (int it = 0; it < 5; ++it) {
            const int e = tid + it * 256;
            if (e < HALFE) bufA[e] = st[it];
        }
    }
    __syncthreads();   // B1: K-A ready

    // issue K half B loads (subs 2,3)
    {
        const unsigned short* gb = ki + (bg4 + 2) * P2 * 8 + rowoff8;
        #pragma unroll
        for (int it = 0; it < 5; ++it) {
            const int e = tid + it * 256;
            if (e < HALFE) {
                const int sl = (e >= NPOS4);
                const int pos = e - (sl ? NPOS4 : 0);
                st[it] = *(const f16x8*)(gb + ((size_t)sl * P2 + pos) * 8);
            }
        }
    }

    float logits0[KS * KS], logits1[KS * KS];
    if (active) {
        // bias init per pixel (shared rel loads)
        const float* rel = (g < 4) ? (rel_h + oc0 * KS) : (rel_w + (oc0 - 128) * KS);
        float qf0[32], qf1[32];
        #pragma unroll
        for (int sub = 0; sub < 4; ++sub)
            #pragma unroll
            for (int j = 0; j < 8; ++j) {
                qf0[sub * 8 + j] = (float)qh0[sub][j];
                qf1[sub * 8 + j] = (float)qh1[sub][j];
            }
        float bd0[KS], bd1[KS];
        #pragma unroll
        for (int t = 0; t < KS; ++t) {
            float s0 = 0.f, s1 = 0.f;
            #pragma unroll
            for (int c = 0; c < 32; ++c) {
                const float r = rel[c * KS + t];
                s0 += qf0[c] * r;
                s1 += qf1[c] * r;
            }
            bd0[t] = s0; bd1[t] = s1;
        }
        #pragma unroll
        for (int i = 0; i < KS; ++i)
            #pragma unroll
            for (int j = 0; j < KS; ++j) {
                logits0[i * KS + j] = (g < 4) ? bd0[i] : bd0[j];
                logits1[i * KS + j] = (g < 4) ? bd1[i] : bd1[j];
            }

        // QK half A: subs 0,1 — row-shared reads
        #pragma unroll
        for (int s = 0; s < 2; ++s) {
            const f16x8 q0 = qh0[s];
            const f16x8 q1 = qh1[s];
            #pragma unroll
            for (int j = 0; j < KS; ++j) {
                #pragma unroll
                for (int ii = 0; ii < 8; ++ii) {
                    const f16x8 kv = bufA[s * NPOS4 + (2 * rp + ii) * WP + cx + j];
                    if (ii < 7)  logits0[ii * KS + j]       = dot8(q0, kv, logits0[ii * KS + j]);
                    if (ii >= 1) logits1[(ii - 1) * KS + j] = dot8(q1, kv, logits1[(ii - 1) * KS + j]);
                }
            }
        }
    }
    // write K half B
    #pragma unroll
    for (int it = 0; it < 5; ++it) {
        const int e = tid + it * 256;
        if (e < HALFE) bufB[e] = st[it];
    }
    __syncthreads();   // B2: K-B ready

    // issue V half A loads (subs 0,1)
    {
        const unsigned short* gb = vi + bg4 * P2 * 8 + rowoff8;
        #pragma unroll
        for (int it = 0; it < 5; ++it) {
            const int e = tid + it * 256;
            if (e < HALFE) {
                const int sl = (e >= NPOS4);
                const int pos = e - (sl ? NPOS4 : 0);
                st[it] = *(const f16x8*)(gb + ((size_t)sl * P2 + pos) * 8);
            }
        }
    }

    if (active) {
        // QK half B: subs 2,3
        #pragma unroll
        for (int s = 0; s < 2; ++s) {
            const f16x8 q0 = qh0[2 + s];
            const f16x8 q1 = qh1[2 + s];
            #pragma unroll
            for (int j = 0; j < KS; ++j) {
                #pragma unroll
                for (int ii = 0; ii < 8; ++ii) {
                    const f16x8 kv = bufB[s * NPOS4 + (2 * rp + ii) * WP + cx + j];
                    if (ii < 7)  logits0[ii * KS + j]       = dot8(q0, kv, logits0[ii * KS + j]);
                    if (ii >= 1) logits1[(ii - 1) * KS + j] = dot8(q1, kv, logits1[(ii - 1) * KS + j]);
                }
            }
        }
        // softmax per pixel
        {
            float m = logits0[0];
            #pragma unroll
            for (int t = 1; t < KS * KS; ++t) m = fmaxf(m, logits0[t]);
            float sum = 0.f;
            #pragma unroll
            for (int t = 0; t < KS * KS; ++t) {
                const float e = __expf(logits0[t] - m);
                logits0[t] = e;
                sum += e;
            }
            const float inv = 1.f / sum;
            #pragma unroll
            for (int t = 0; t < KS * KS; ++t) logits0[t] *= inv;
        }
        {
            float m = logits1[0];
            #pragma unroll
            for (int t = 1; t < KS * KS; ++t) m = fmaxf(m, logits1[t]);
            float sum = 0.f;
            #pragma unroll
            for (int t = 0; t < KS * KS; ++t) {
                const float e = __expf(logits1[t] - m);
                logits1[t] = e;
                sum += e;
            }
            const float inv = 1.f / sum;
            #pragma unroll
            for (int t = 0; t < KS * KS; ++t) logits1[t] *= inv;
        }
    }
    // write V half A
    #pragma unroll
    for (int it = 0; it < 5; ++it) {
        const int e = tid + it * 256;
        if (e < HALFE) bufA[e] = st[it];
    }
    __syncthreads();   // B3: V-A ready

    // issue V half B loads (subs 2,3)
    {
        const unsigned short* gb = vi + (bg4 + 2) * P2 * 8 + rowoff8;
        #pragma unroll
        for (int it = 0; it < 5; ++it) {
            const int e = tid + it * 256;
            if (e < HALFE) {
                const int sl = (e >= NPOS4);
                const int pos = e - (sl ? NPOS4 : 0);
                st[it] = *(const f16x8*)(gb + ((size_t)sl * P2 + pos) * 8);
            }
        }
    }

    if (active) {
        // PV half A: subs 0,1 -> channels oc0 + s*8
        #pragma unroll
        for (int s = 0; s < 2; ++s) {
            float a0[8] = {}, a1[8] = {};
            #pragma unroll
            for (int j = 0; j < KS; ++j) {
                #pragma unroll
                for (int ii = 0; ii < 8; ++ii) {
                    const f16x8 v = bufA[s * NPOS4 + (2 * rp + ii) * WP + cx + j];
                    if (ii < 7) {
                        const float wt = logits0[ii * KS + j];
                        #pragma unroll
                        for (int c = 0; c < 8; ++c) a0[c] += wt * (float)v[c];
                    }
                    if (ii >= 1) {
                        const float wt = logits1[(ii - 1) * KS + j];
                        #pragma unroll
                        for (int c = 0; c < 8; ++c) a1[c] += wt * (float)v[c];
                    }
                }
            }
            float* op0 = out + ((size_t)b * OUTC + oc0 + s * 8) * P1 + pix0;
            float* op1 = out + ((size_t)b * OUTC + oc0 + s * 8) * P1 + pix1;
            #pragma unroll
            for (int c = 0; c < 8; ++c) {
                op0[(size_t)c * P1] = a0[c];
                op1[(size_t)c * P1] = a1[c];
            }
        }
    }
    // write V half B
    #pragma unroll
    for (int it = 0; it < 5; ++it) {
        const int e = tid + it * 256;
        if (e < HALFE) bufB[e] = st[it];
    }
    __syncthreads();   // B4: V-B ready

    if (active) {
        // PV half B: subs 2,3 -> channels oc0 + 16 + s*8
        #pragma unroll
        for (int s = 0; s < 2; ++s) {
            float a0[8] = {}, a1[8] = {};
            #pragma unroll
            for (int j = 0; j < KS; ++j) {
                #pragma unroll
                for (int ii = 0; ii < 8; ++ii) {
                    const f16x8 v = bufB[s * NPOS4 + (2 * rp + ii) * WP + cx + j];
                    if (ii < 7) {
                        const float wt = logits0[ii * KS + j];
                        #pragma unroll
                        for (int c = 0; c < 8; ++c) a0[c] += wt * (float)v[c];
                    }
                    if (ii >= 1) {
                        const float wt = logits1[(ii - 1) * KS + j];
                        #pragma unroll
                        for (int c = 0; c < 8; ++c) a1[c] += wt * (float)v[c];
                    }
                }
            }
            float* op0 = out + ((size_t)b * OUTC + oc0 + 16 + s * 8) * P1 + pix0;
            float* op1 = out + ((size_t)b * OUTC + oc0 + 16 + s * 8) * P1 + pix1;
            #pragma unroll
            for (int c = 0; c < 8; ++c) {
                op0[(size_t)c * P1] = a0[c];
                op1[(size_t)c * P1] = a1[c];
            }
        }
    }
}

extern "C" void kernel_launch(void* const* d_in, const int* in_sizes, int n_in,
                              void* d_out, int out_size, void* d_ws, size_t ws_size,
                              hipStream_t stream) {
    const float* fm = (const float*)d_in[0];
    const float* wq = (const float*)d_in[1];
    const float* wk = (const float*)d_in[2];
    const float* wv = (const float*)d_in[3];
    const float* rh = (const float*)d_in[4];
    const float* rw = (const float*)d_in[5];
    float* out = (float*)d_out;

    unsigned short* ws = (unsigned short*)d_ws;
    unsigned short* qi = ws;                             // 2*8*4*3136*8 fp16
    unsigned short* ki = qi + (size_t)B * OUTC * P1;     // 2*8*4*3844*8 fp16
    unsigned short* vi = ki + (size_t)B * OUTC * P2;

    gemm_kernel<<<dim3(31, 6, B), 256, 0, stream>>>(fm, wq, wk, wv, qi, ki, vi);
    attn_kernel<<<dim3(H / 4, G, B), 256, 0, stream>>>(qi, ki, vi, rh, rw, out);
}

// Round 7
// 108.647 us; speedup vs baseline: 1.1249x; 1.0431x over previous
//
#include <hip/hip_runtime.h>
#include <hip/hip_bf16.h>

// Problem constants
#define B    2
#define CIN  256
#define H    56
#define W    56
#define OUTC 256
#define KS   7
#define PAD  3
#define G    8
#define CG   32
#define HP   62           // H + 2*PAD
#define WP   62
#define P1   (H * W)      // 3136
#define P2   (HP * WP)    // 3844

typedef __attribute__((ext_vector_type(2))) _Float16 h2;
typedef __attribute__((ext_vector_type(8))) _Float16 f16x8;
typedef __attribute__((ext_vector_type(4))) float f32x4;

__device__ inline unsigned short f2h(float f) {    // RNE float->fp16 bits
    const _Float16 h = (_Float16)f;
    return *(const unsigned short*)&h;
}

__device__ inline float fdot2(h2 a, h2 b, float c) {
#if defined(__has_builtin)
#if __has_builtin(__builtin_amdgcn_fdot2)
    return __builtin_amdgcn_fdot2(a, b, c, false);
#else
    return c + (float)a[0] * (float)b[0] + (float)a[1] * (float)b[1];
#endif
#else
    return c + (float)a[0] * (float)b[0] + (float)a[1] * (float)b[1];
#endif
}

__device__ inline float dot8(const f16x8 q, const f16x8 k, float s) {
    s = fdot2((h2){q[0], q[1]}, (h2){k[0], k[1]}, s);
    s = fdot2((h2){q[2], q[3]}, (h2){k[2], k[3]}, s);
    s = fdot2((h2){q[4], q[5]}, (h2){k[4], k[5]}, s);
    s = fdot2((h2){q[6], q[7]}, (h2){k[6], k[7]}, s);
    return s;
}

// ---------------------------------------------------------------------------
// Fused fp32->fp16 + MFMA GEMM: grid (31, 6, B).  (unchanged from R6)
//   y<2  : q GEMM  (w_q x fm_t1), x<25 only (N=P1)
//   y>=2 : kv GEMM (w_k rows 0..255, w_v rows 256..511 x padded fm_t0, N=P2)
// 128x128 tile, 4 waves, BK=32; staging converts fp32 inputs inline.
// Double-buffered LDS -> one barrier per K-step.
// Epilogue writes fp16 INTERLEAVED planes: base[((b*8+g)*4+sub)*Pstr+n]*8+l8.
// ---------------------------------------------------------------------------
#define ASTR 40
__global__ __launch_bounds__(256, 2) void gemm_kernel(const float* __restrict__ fm,
                                                      const float* __restrict__ wq,
                                                      const float* __restrict__ wk,
                                                      const float* __restrict__ wv,
                                                      unsigned short* __restrict__ qi,
                                                      unsigned short* __restrict__ ki,
                                                      unsigned short* __restrict__ vi) {
    const int b = blockIdx.z;
    const bool isQ = blockIdx.y < 2;
    if (isQ && blockIdx.x >= 25) return;
    const int o0 = (isQ ? blockIdx.y : (blockIdx.y - 2)) * 128;   // 0..383
    const int n0 = blockIdx.x * 128;
    const int Nreal = isQ ? P1 : P2;
    const int Pstr  = isQ ? P1 : P2;

    const float* Wsrc;
    int orow0;
    if (isQ)            { Wsrc = wq; orow0 = o0; }
    else if (o0 < 256)  { Wsrc = wk; orow0 = o0; }
    else                { Wsrc = wv; orow0 = o0 - 256; }

    __shared__ unsigned short Alds[2][128 * ASTR];
    __shared__ unsigned short Blds[2][128 * ASTR];
    const int tid = threadIdx.x;
    const int lane = tid & 63;
    const int wave = tid >> 6;
    const int wr = (wave >> 1) * 64;
    const int wc = (wave & 1) * 64;
    const int lrow = lane & 15;
    const int quad = lane >> 4;

    const int arow = tid & 127;
    const int akc  = (tid >> 7) * 16;

    const int n = n0 + arow;
    int srcoff = -1;
    if (isQ) {
        if (n < P1) srcoff = n;
    } else {
        if (n < P2) {
            const int y = n / WP, x = n - y * WP;
            const int iy = y - PAD, ix = x - PAD;
            if (iy >= 0 && iy < H && ix >= 0 && ix < W) srcoff = iy * W + ix;
        }
    }
    const float* fmB = fm + ((size_t)b * (2 * CIN) + (isQ ? CIN : 0)) * P1;
    const float* wrow = Wsrc + (size_t)orow0 * CIN + (size_t)arow * CIN + akc;

    f32x4 acc[4][4] = {};

    float av[16], bv[16];
    {
        const float4 a0 = ((const float4*)wrow)[0];
        const float4 a1 = ((const float4*)wrow)[1];
        const float4 a2 = ((const float4*)wrow)[2];
        const float4 a3 = ((const float4*)wrow)[3];
        av[0]=a0.x; av[1]=a0.y; av[2]=a0.z; av[3]=a0.w;
        av[4]=a1.x; av[5]=a1.y; av[6]=a1.z; av[7]=a1.w;
        av[8]=a2.x; av[9]=a2.y; av[10]=a2.z; av[11]=a2.w;
        av[12]=a3.x; av[13]=a3.y; av[14]=a3.z; av[15]=a3.w;
        #pragma unroll
        for (int j = 0; j < 16; ++j)
            bv[j] = (srcoff >= 0) ? fmB[(size_t)(akc + j) * P1 + srcoff] : 0.f;
    }

    for (int kb = 0; kb < CIN / 32; ++kb) {
        const int cur = kb & 1;
        unsigned short* alp = Alds[cur] + arow * ASTR + akc;
        unsigned short* blp = Blds[cur] + arow * ASTR + akc;
        {
            f16x8 p0, p1, p2, p3;
            #pragma unroll
            for (int j = 0; j < 8; ++j) {
                p0[j] = (_Float16)av[j];
                p1[j] = (_Float16)av[8 + j];
                p2[j] = (_Float16)bv[j];
                p3[j] = (_Float16)bv[8 + j];
            }
            *(f16x8*)(alp)     = p0;
            *(f16x8*)(alp + 8) = p1;
            *(f16x8*)(blp)     = p2;
            *(f16x8*)(blp + 8) = p3;
        }
        __syncthreads();                    // buf[cur] staged; one barrier/step
        if (kb < CIN / 32 - 1) {
            const int c0 = (kb + 1) * 32 + akc;
            const float* wnext = wrow + (kb + 1) * 32;
            const float4 a0 = ((const float4*)wnext)[0];
            const float4 a1 = ((const float4*)wnext)[1];
            const float4 a2 = ((const float4*)wnext)[2];
            const float4 a3 = ((const float4*)wnext)[3];
            av[0]=a0.x; av[1]=a0.y; av[2]=a0.z; av[3]=a0.w;
            av[4]=a1.x; av[5]=a1.y; av[6]=a1.z; av[7]=a1.w;
            av[8]=a2.x; av[9]=a2.y; av[10]=a2.z; av[11]=a2.w;
            av[12]=a3.x; av[13]=a3.y; av[14]=a3.z; av[15]=a3.w;
            #pragma unroll
            for (int j = 0; j < 16; ++j)
                bv[j] = (srcoff >= 0) ? fmB[(size_t)(c0 + j) * P1 + srcoff] : 0.f;
        }
        f16x8 af[4], bfr[4];
        #pragma unroll
        for (int mi = 0; mi < 4; ++mi)
            af[mi] = *(const f16x8*)&Alds[cur][(wr + mi * 16 + lrow) * ASTR + quad * 8];
        #pragma unroll
        for (int ni = 0; ni < 4; ++ni)
            bfr[ni] = *(const f16x8*)&Blds[cur][(wc + ni * 16 + lrow) * ASTR + quad * 8];
        #pragma unroll
        for (int mi = 0; mi < 4; ++mi)
            #pragma unroll
            for (int ni = 0; ni < 4; ++ni)
                acc[mi][ni] = __builtin_amdgcn_mfma_f32_16x16x32_f16(af[mi], bfr[ni], acc[mi][ni], 0, 0, 0);
    }

    #pragma unroll
    for (int mi = 0; mi < 4; ++mi) {
        const int gmBase = o0 + wr + mi * 16 + quad * 4;
        int ch0;
        unsigned short* base;
        if (isQ)               { ch0 = gmBase;       base = qi; }
        else if (gmBase < 256) { ch0 = gmBase;       base = ki; }
        else                   { ch0 = gmBase - 256; base = vi; }
        const int g   = ch0 >> 5;
        const int sub = (ch0 >> 3) & 3;
        const int l8  = ch0 & 7;
        unsigned short* pbase = base + ((((size_t)b * 8 + g) * 4 + sub) * Pstr) * 8 + l8;
        #pragma unroll
        for (int ni = 0; ni < 4; ++ni) {
            const int gn = n0 + wc + ni * 16 + lrow;
            if (gn < Nreal) {
                ushort4 pk;
                pk.x = f2h(acc[mi][ni][0]);
                pk.y = f2h(acc[mi][ni][1]);
                pk.z = f2h(acc[mi][ni][2]);
                pk.w = f2h(acc[mi][ni][3]);
                *(ushort4*)(pbase + (size_t)gn * 8) = pk;
            }
        }
    }
}

// ---------------------------------------------------------------------------
// Grouped 7x7 attention (R0 structure, 2-ROW strips for inter-block overlap):
// Block = 2 pixel rows x 56 cols for one (b,g): 128 threads, 56 compute-
// active (cx = tid, pixels r0 and r0+1). Grid (28, 8, 2) = 448 blocks ->
// ~2 blocks/CU on most CUs; the two co-resident blocks are phase-
// independent, so one block's QK/PV compute hides the other's global
// staging latency (R0's 224-block layout left every CU with a single
// block and fully-exposed staging phases).
// Window = 8 padded rows x 62 = 496 pos; halves of 16 ch (2 f16x8 subs).
// LDS: f16x8 sbuf[2 halves][2 subs x 496] = 31,744 B (2 blocks/CU fit).
// Read sharing: per tap-col j, 8 row-reads (ii=0..7) serve pixel0 taps
// ii<7 and pixel1 taps ii>=1; lane stride 16 B (conflict-free).
// 4-barrier K/V channel-split pipeline identical to R0.
// ---------------------------------------------------------------------------
#define NPOS4 496    // 8 * 62
#define HALFE 992    // 2 subs * 496
__global__ __launch_bounds__(128) void attn_kernel(const unsigned short* __restrict__ qi,
                                                   const unsigned short* __restrict__ ki,
                                                   const unsigned short* __restrict__ vi,
                                                   const float* __restrict__ rel_h,
                                                   const float* __restrict__ rel_w,
                                                   float* __restrict__ out) {
    __shared__ f16x8 sbuf[2 * HALFE];   // 31,744 B

    const int b  = blockIdx.z;
    const int g  = blockIdx.y;
    const int r0 = blockIdx.x * 2;      // first pixel row of 2-row strip
    const int oc0 = g * CG;
    const int tid = threadIdx.x;
    const bool active = tid < 56;
    const int cx = tid;                 // 0..55 (when active)
    const int pix0 = r0 * W + cx;
    const int pix1 = pix0 + W;

    const size_t bg4 = ((size_t)b * 8 + g) * 4;
    const size_t rowoff8 = ((size_t)r0 * WP) * 8;

    f16x8* bufA = sbuf;
    f16x8* bufB = sbuf + HALFE;

    // q for both pixels (issued before staging barrier)
    f16x8 qh0[4], qh1[4];
    if (active) {
        #pragma unroll
        for (int sub = 0; sub < 4; ++sub) {
            qh0[sub] = *(const f16x8*)(qi + ((bg4 + sub) * P1 + pix0) * 8);
            qh1[sub] = *(const f16x8*)(qi + ((bg4 + sub) * P1 + pix1) * 8);
        }
    }

    f16x8 st[8];
    // ---- stage K half A (subs 0,1) ----
    {
        const unsigned short* gb = ki + bg4 * P2 * 8 + rowoff8;
        #pragma unroll
        for (int it = 0; it < 8; ++it) {
            const int e = tid + it * 128;
            if (e < HALFE) {
                const int sl = (e >= NPOS4);
                const int pos = e - (sl ? NPOS4 : 0);
                st[it] = *(const f16x8*)(gb + ((size_t)sl * P2 + pos) * 8);
            }
        }
        #pragma unroll
        for (int it = 0; it < 8; ++it) {
            const int e = tid + it * 128;
            if (e < HALFE) bufA[e] = st[it];
        }
    }
    __syncthreads();   // B1: K-A ready

    // issue K half B loads (subs 2,3)
    {
        const unsigned short* gb = ki + (bg4 + 2) * P2 * 8 + rowoff8;
        #pragma unroll
        for (int it = 0; it < 8; ++it) {
            const int e = tid + it * 128;
            if (e < HALFE) {
                const int sl = (e >= NPOS4);
                const int pos = e - (sl ? NPOS4 : 0);
                st[it] = *(const f16x8*)(gb + ((size_t)sl * P2 + pos) * 8);
            }
        }
    }

    float logits0[KS * KS], logits1[KS * KS];
    if (active) {
        // bias init per pixel (shared rel loads)
        const float* rel = (g < 4) ? (rel_h + oc0 * KS) : (rel_w + (oc0 - 128) * KS);
        float qf0[32], qf1[32];
        #pragma unroll
        for (int sub = 0; sub < 4; ++sub)
            #pragma unroll
            for (int j = 0; j < 8; ++j) {
                qf0[sub * 8 + j] = (float)qh0[sub][j];
                qf1[sub * 8 + j] = (float)qh1[sub][j];
            }
        float bd0[KS], bd1[KS];
        #pragma unroll
        for (int t = 0; t < KS; ++t) {
            float s0 = 0.f, s1 = 0.f;
            #pragma unroll
            for (int c = 0; c < 32; ++c) {
                const float r = rel[c * KS + t];
                s0 += qf0[c] * r;
                s1 += qf1[c] * r;
            }
            bd0[t] = s0; bd1[t] = s1;
        }
        #pragma unroll
        for (int i = 0; i < KS; ++i)
            #pragma unroll
            for (int j = 0; j < KS; ++j) {
                logits0[i * KS + j] = (g < 4) ? bd0[i] : bd0[j];
                logits1[i * KS + j] = (g < 4) ? bd1[i] : bd1[j];
            }

        // QK half A: subs 0,1 — row-shared reads
        #pragma unroll
        for (int s = 0; s < 2; ++s) {
            const f16x8 q0 = qh0[s];
            const f16x8 q1 = qh1[s];
            #pragma unroll
            for (int j = 0; j < KS; ++j) {
                #pragma unroll
                for (int ii = 0; ii < 8; ++ii) {
                    const f16x8 kv = bufA[s * NPOS4 + ii * WP + cx + j];
                    if (ii < 7)  logits0[ii * KS + j]       = dot8(q0, kv, logits0[ii * KS + j]);
                    if (ii >= 1) logits1[(ii - 1) * KS + j] = dot8(q1, kv, logits1[(ii - 1) * KS + j]);
                }
            }
        }
    }
    // write K half B
    #pragma unroll
    for (int it = 0; it < 8; ++it) {
        const int e = tid + it * 128;
        if (e < HALFE) bufB[e] = st[it];
    }
    __syncthreads();   // B2: K-B ready

    // issue V half A loads (subs 0,1)
    {
        const unsigned short* gb = vi + bg4 * P2 * 8 + rowoff8;
        #pragma unroll
        for (int it = 0; it < 8; ++it) {
            const int e = tid + it * 128;
            if (e < HALFE) {
                const int sl = (e >= NPOS4);
                const int pos = e - (sl ? NPOS4 : 0);
                st[it] = *(const f16x8*)(gb + ((size_t)sl * P2 + pos) * 8);
            }
        }
    }

    if (active) {
        // QK half B: subs 2,3
        #pragma unroll
        for (int s = 0; s < 2; ++s) {
            const f16x8 q0 = qh0[2 + s];
            const f16x8 q1 = qh1[2 + s];
            #pragma unroll
            for (int j = 0; j < KS; ++j) {
                #pragma unroll
                for (int ii = 0; ii < 8; ++ii) {
                    const f16x8 kv = bufB[s * NPOS4 + ii * WP + cx + j];
                    if (ii < 7)  logits0[ii * KS + j]       = dot8(q0, kv, logits0[ii * KS + j]);
                    if (ii >= 1) logits1[(ii - 1) * KS + j] = dot8(q1, kv, logits1[(ii - 1) * KS + j]);
                }
            }
        }
        // softmax per pixel
        {
            float m = logits0[0];
            #pragma unroll
            for (int t = 1; t < KS * KS; ++t) m = fmaxf(m, logits0[t]);
            float sum = 0.f;
            #pragma unroll
            for (int t = 0; t < KS * KS; ++t) {
                const float e = __expf(logits0[t] - m);
                logits0[t] = e;
                sum += e;
            }
            const float inv = 1.f / sum;
            #pragma unroll
            for (int t = 0; t < KS * KS; ++t) logits0[t] *= inv;
        }
        {
            float m = logits1[0];
            #pragma unroll
            for (int t = 1; t < KS * KS; ++t) m = fmaxf(m, logits1[t]);
            float sum = 0.f;
            #pragma unroll
            for (int t = 0; t < KS * KS; ++t) {
                const float e = __expf(logits1[t] - m);
                logits1[t] = e;
                sum += e;
            }
            const float inv = 1.f / sum;
            #pragma unroll
            for (int t = 0; t < KS * KS; ++t) logits1[t] *= inv;
        }
    }
    // write V half A
    #pragma unroll
    for (int it = 0; it < 8; ++it) {
        const int e = tid + it * 128;
        if (e < HALFE) bufA[e] = st[it];
    }
    __syncthreads();   // B3: V-A ready

    // issue V half B loads (subs 2,3)
    {
        const unsigned short* gb = vi + (bg4 + 2) * P2 * 8 + rowoff8;
        #pragma unroll
        for (int it = 0; it < 8; ++it) {
            const int e = tid + it * 128;
            if (e < HALFE) {
                const int sl = (e >= NPOS4);
                const int pos = e - (sl ? NPOS4 : 0);
                st[it] = *(const f16x8*)(gb + ((size_t)sl * P2 + pos) * 8);
            }
        }
    }

    if (active) {
        // PV half A: subs 0,1 -> channels oc0 + s*8
        #pragma unroll
        for (int s = 0; s < 2; ++s) {
            float a0[8] = {}, a1[8] = {};
            #pragma unroll
            for (int j = 0; j < KS; ++j) {
                #pragma unroll
                for (int ii = 0; ii < 8; ++ii) {
                    const f16x8 v = bufA[s * NPOS4 + ii * WP + cx + j];
                    if (ii < 7) {
                        const float wt = logits0[ii * KS + j];
                        #pragma unroll
                        for (int c = 0; c < 8; ++c) a0[c] += wt * (float)v[c];
                    }
                    if (ii >= 1) {
                        const float wt = logits1[(ii - 1) * KS + j];
                        #pragma unroll
                        for (int c = 0; c < 8; ++c) a1[c] += wt * (float)v[c];
                    }
                }
            }
            float* op0 = out + ((size_t)b * OUTC + oc0 + s * 8) * P1 + pix0;
            float* op1 = out + ((size_t)b * OUTC + oc0 + s * 8) * P1 + pix1;
            #pragma unroll
            for (int c = 0; c < 8; ++c) {
                op0[(size_t)c * P1] = a0[c];
                op1[(size_t)c * P1] = a1[c];
            }
        }
    }
    // write V half B
    #pragma unroll
    for (int it = 0; it < 8; ++it) {
        const int e = tid + it * 128;
        if (e < HALFE) bufB[e] = st[it];
    }
    __syncthreads();   // B4: V-B ready

    if (active) {
        // PV half B: subs 2,3 -> channels oc0 + 16 + s*8
        #pragma unroll
        for (int s = 0; s < 2; ++s) {
            float a0[8] = {}, a1[8] = {};
            #pragma unroll
            for (int j = 0; j < KS; ++j) {
                #pragma unroll
                for (int ii = 0; ii < 8; ++ii) {
                    const f16x8 v = bufB[s * NPOS4 + ii * WP + cx + j];
                    if (ii < 7) {
                        const float wt = logits0[ii * KS + j];
                        #pragma unroll
                        for (int c = 0; c < 8; ++c) a0[c] += wt * (float)v[c];
                    }
                    if (ii >= 1) {
                        const float wt = logits1[(ii - 1) * KS + j];
                        #pragma unroll
                        for (int c = 0; c < 8; ++c) a1[c] += wt * (float)v[c];
                    }
                }
            }
            float* op0 = out + ((size_t)b * OUTC + oc0 + 16 + s * 8) * P1 + pix0;
            float* op1 = out + ((size_t)b * OUTC + oc0 + 16 + s * 8) * P1 + pix1;
            #pragma unroll
            for (int c = 0; c < 8; ++c) {
                op0[(size_t)c * P1] = a0[c];
                op1[(size_t)c * P1] = a1[c];
            }
        }
    }
}

extern "C" void kernel_launch(void* const* d_in, const int* in_sizes, int n_in,
                              void* d_out, int out_size, void* d_ws, size_t ws_size,
                              hipStream_t stream) {
    const float* fm = (const float*)d_in[0];
    const float* wq = (const float*)d_in[1];
    const float* wk = (const float*)d_in[2];
    const float* wv = (const float*)d_in[3];
    const float* rh = (const float*)d_in[4];
    const float* rw = (const float*)d_in[5];
    float* out = (float*)d_out;

    unsigned short* ws = (unsigned short*)d_ws;
    unsigned short* qi = ws;                             // 2*8*4*3136*8 fp16
    unsigned short* ki = qi + (size_t)B * OUTC * P1;     // 2*8*4*3844*8 fp16
    unsigned short* vi = ki + (size_t)B * OUTC * P2;

    gemm_kernel<<<dim3(31, 6, B), 256, 0, stream>>>(fm, wq, wk, wv, qi, ki, vi);
    attn_kernel<<<dim3(H / 2, G, B), 128, 0, stream>>>(qi, ki, vi, rh, rw, out);
}